// Round 4
// baseline (375.052 us; speedup 1.0000x reference)
//
#include <hip/hip_runtime.h>
#include <hip/hip_bf16.h>
#include <math.h>

#define BB 8
#define TT 2048
#define CC 1024
#define HH 64
#define NROW (BB*TT)          // 16384
#define NST (NROW*HH)         // 1048576 elements per output component
#define KK2 2048              // combined GEMM K = 2C
#define NN 384                // combined GEMM N = 6*64

typedef __attribute__((ext_vector_type(8))) short short8;
typedef __attribute__((ext_vector_type(4))) short short4v;
typedef __attribute__((ext_vector_type(4))) float f32x4;

static __device__ inline unsigned pk_bf16(float a, float b) {
    __hip_bfloat162 h = __float22bfloat162_rn(make_float2(a, b));
    unsigned u; __builtin_memcpy(&u, &h, 4); return u;
}
static __device__ inline short f2bf_s(float a) {
    __hip_bfloat16 h = __float2bfloat16(a);
    short s; __builtin_memcpy(&s, &h, 2); return s;
}
static __device__ inline short8 neg8(short8 a) {
    short8 r;
    #pragma unroll
    for (int i = 0; i < 8; ++i) r[i] = a[i] ^ (short)0x8000;
    return r;
}

// ---------------------------------------------------------------------------
// Kernel 0: build Bt[n][k] bf16 for the projection GEMM.
// n = 64*g + h, g in [kr,ki,qr,qi,vr,vi]; real: [Wr;-Wi], imag: [Wi;Wr].
// ---------------------------------------------------------------------------
__global__ __launch_bounds__(256) void prep_kernel(
    const float* __restrict__ Wkr, const float* __restrict__ Wki,
    const float* __restrict__ Wqr, const float* __restrict__ Wqi,
    const float* __restrict__ Wvr, const float* __restrict__ Wvi,
    short* __restrict__ Bt)
{
    const int n = blockIdx.x;
    const int g = n >> 6, h = n & 63;
    const int p = g >> 1;
    const bool im = g & 1;
    const float* Wr = (p == 0) ? Wkr : (p == 1) ? Wqr : Wvr;
    const float* Wi = (p == 0) ? Wki : (p == 1) ? Wqi : Wvi;
    const float* W1 = im ? Wi : Wr;
    const float* W2 = im ? Wr : Wi;
    const float s2 = im ? 1.f : -1.f;

    #pragma unroll
    for (int j = 0; j < 8; ++j) {
        int k = threadIdx.x + 256 * j;
        float v = (k < CC) ? W1[k * HH + h] : s2 * W2[(k - CC) * HH + h];
        Bt[(size_t)n * KK2 + k] = f2bf_s(v);
    }
}

// ---------------------------------------------------------------------------
// Kernel 1: bf16 MFMA GEMM. BM=64 BN=128 BK=64, grid (256,3)=768 blocks.
// 4 waves, each owns a 64x32 slice (wc = n-slice). k,q -> G[16384][384];
// v (blockIdx.y==2) -> VT[comp][b][h][t] directly (fused transpose).
// ---------------------------------------------------------------------------
#define BK 64
#define LDP 72

__global__ __launch_bounds__(256) void proj_gemm(
    const float* __restrict__ xr, const float* __restrict__ xi,
    const short* __restrict__ Bt,
    short* __restrict__ G, short* __restrict__ VT)
{
    __shared__ __attribute__((aligned(16))) short sA[64 * LDP];
    __shared__ __attribute__((aligned(16))) short sB[128 * LDP];

    const int tid = threadIdx.x;
    const int mbase = blockIdx.x * 64;
    const int n0 = blockIdx.y * 128;

    const int wave = tid >> 6, lane = tid & 63;
    const int wc = wave;                     // n-slice of 32
    const int quad = lane >> 4, lm = lane & 15;

    f32x4 acc[4][2] = {};

    for (int ks = 0; ks < KK2 / BK; ++ks) {
        const float* __restrict__ srcA = (ks < 16) ? xr : xi;
        const int kc = (ks & 15) * BK;
        float4 av[4];
        #pragma unroll
        for (int j = 0; j < 4; ++j) {
            int id = tid + 256 * j;
            int r = id >> 4, c4 = id & 15;
            av[j] = *(const float4*)&srcA[(size_t)(mbase + r) * CC + kc + c4 * 4];
        }
        uint4 bv[4];
        #pragma unroll
        for (int j = 0; j < 4; ++j) {
            int id = tid + 256 * j;
            int nn = id >> 3, c8 = id & 7;
            bv[j] = *(const uint4*)&Bt[(size_t)(n0 + nn) * KK2 + ks * BK + c8 * 8];
        }
        __syncthreads();

        #pragma unroll
        for (int j = 0; j < 4; ++j) {
            int id = tid + 256 * j;
            int r = id >> 4, c4 = id & 15;
            uint2 pkd;
            pkd.x = pk_bf16(av[j].x, av[j].y);
            pkd.y = pk_bf16(av[j].z, av[j].w);
            *(uint2*)&sA[r * LDP + c4 * 4] = pkd;
        }
        #pragma unroll
        for (int j = 0; j < 4; ++j) {
            int id = tid + 256 * j;
            int nn = id >> 3, c8 = id & 7;
            *(uint4*)&sB[nn * LDP + c8 * 8] = bv[j];
        }
        __syncthreads();

        #pragma unroll
        for (int kk = 0; kk < 2; ++kk) {
            short8 af[4], bf[2];
            #pragma unroll
            for (int mi = 0; mi < 4; ++mi)
                af[mi] = *(const short8*)&sA[(16*mi + lm) * LDP + kk*32 + quad*8];
            #pragma unroll
            for (int ni = 0; ni < 2; ++ni)
                bf[ni] = *(const short8*)&sB[(32*wc + 16*ni + lm) * LDP + kk*32 + quad*8];
            #pragma unroll
            for (int mi = 0; mi < 4; ++mi)
                #pragma unroll
                for (int ni = 0; ni < 2; ++ni)
                    acc[mi][ni] = __builtin_amdgcn_mfma_f32_16x16x32_bf16(
                        af[mi], bf[ni], acc[mi][ni], 0, 0, 0);
        }
    }

    if (blockIdx.y < 2) {
        // columns y*128 + 32*wc + 16*ni + lm  ->  G (token-major)
        #pragma unroll
        for (int mi = 0; mi < 4; ++mi)
            #pragma unroll
            for (int ni = 0; ni < 2; ++ni)
                #pragma unroll
                for (int r = 0; r < 4; ++r) {
                    int row = mbase + 16*mi + quad*4 + r;
                    int col = n0 + 32*wc + 16*ni + lm;
                    G[(size_t)row * NN + col] = f2bf_s(acc[mi][ni][r]);
                }
    } else {
        // v block: write transposed VT[comp][b][h][t], 8B stores (4 tokens)
        const int comp = wc >> 1;
        const int b = mbase >> 11;
        const int tb = mbase & 2047;
        #pragma unroll
        for (int mi = 0; mi < 4; ++mi)
            #pragma unroll
            for (int ni = 0; ni < 2; ++ni) {
                int h = 32*(wc & 1) + 16*ni + lm;
                int t0 = tb + 16*mi + quad*4;
                short4v pk;
                #pragma unroll
                for (int r = 0; r < 4; ++r) pk[r] = f2bf_s(acc[mi][ni][r]);
                *(short4v*)&VT[(((size_t)comp*BB + b)*64 + h)*TT + t0] = pk;
            }
    }
}

// ---------------------------------------------------------------------------
// Kernel 2: MFMA flash attention. Wave-autonomous 16-row q-tiles; 4 waves/block
// split the k-range (kt % 4 == wave) and merge (m,l,O) via LDS at the end.
// grid = (128 q-tiles, 8 b), 256 threads. q-tiles processed longest-first.
// ---------------------------------------------------------------------------
#define PLDS 72

__global__ __launch_bounds__(256) void attn_kernel(
    const short* __restrict__ G,
    const short* __restrict__ VT,
    float* __restrict__ out)
{
    __shared__ float comb[4][16][128];
    __shared__ float cmw[4][16], clw[4][16];

    const int tid = threadIdx.x;
    const int wave = tid >> 6, lane = tid & 63;
    const int quad = lane >> 4, lm = lane & 15;
    const int j = (int)(gridDim.x - 1) - (int)blockIdx.x;   // longest first
    const int b = blockIdx.y;
    const int qbase = j * 16;
    const int nkt = (j >> 2) + 1;    // k-tiles of 64 tokens

    const short* Qrow = G + ((size_t)(b*TT + qbase + lm)) * NN + 128;
    short8 A1[4], A2[4];
    #pragma unroll
    for (int ks = 0; ks < 4; ++ks)
        A1[ks] = *(const short8*)(Qrow + ks*32 + quad*8);
    A2[0] = A1[2]; A2[1] = A1[3];
    A2[2] = neg8(A1[0]); A2[3] = neg8(A1[1]);

    f32x4 Or[4], Oi[4];
    #pragma unroll
    for (int h = 0; h < 4; ++h)
        #pragma unroll
        for (int r = 0; r < 4; ++r) { Or[h][r] = 0.f; Oi[h][r] = 0.f; }
    float m[4], l[4];
    #pragma unroll
    for (int r = 0; r < 4; ++r) { m[r] = -INFINITY; l[r] = 0.f; }

    short* Pw = (short*)&comb[wave][0][0];
    const short* Vrb = VT + (size_t)b * 64 * TT;
    const short* Vib = Vrb + (size_t)BB * 64 * TT;

    for (int kt = wave; kt < nkt; kt += 4) {
        const int kb = kt * 64;
        const short* Kt = G + ((size_t)(b*TT + kb)) * NN;

        f32x4 mag[4];
        #pragma unroll
        for (int nt = 0; nt < 4; ++nt) {
            const short* Krow = Kt + (size_t)(nt*16 + lm) * NN;
            short8 Bf[4];
            #pragma unroll
            for (int ks = 0; ks < 4; ++ks)
                Bf[ks] = *(const short8*)(Krow + ks*32 + quad*8);
            f32x4 sr = {0.f,0.f,0.f,0.f}, si = {0.f,0.f,0.f,0.f};
            #pragma unroll
            for (int ks = 0; ks < 4; ++ks) {
                sr = __builtin_amdgcn_mfma_f32_16x16x32_bf16(A1[ks], Bf[ks], sr, 0,0,0);
                si = __builtin_amdgcn_mfma_f32_16x16x32_bf16(A2[ks], Bf[ks], si, 0,0,0);
            }
            int tok = kb + nt*16 + lm;
            #pragma unroll
            for (int r = 0; r < 4; ++r) {
                float v = sqrtf(fmaf(sr[r], sr[r], fmaf(si[r], si[r], 1e-4f))) * 0.125f;
                int qrow = qbase + quad*4 + r;
                mag[nt][r] = (tok > qrow) ? -INFINITY : v;
            }
        }

        float tm[4];
        #pragma unroll
        for (int r = 0; r < 4; ++r)
            tm[r] = fmaxf(fmaxf(mag[0][r], mag[1][r]), fmaxf(mag[2][r], mag[3][r]));
        #pragma unroll
        for (int d = 1; d < 16; d <<= 1)
            #pragma unroll
            for (int r = 0; r < 4; ++r)
                tm[r] = fmaxf(tm[r], __shfl_xor(tm[r], d, 16));

        float al[4], ps[4];
        #pragma unroll
        for (int r = 0; r < 4; ++r) {
            float mn = fmaxf(m[r], tm[r]);
            al[r] = __expf(m[r] - mn);
            m[r] = mn;
            ps[r] = 0.f;
        }
        #pragma unroll
        for (int nt = 0; nt < 4; ++nt)
            #pragma unroll
            for (int r = 0; r < 4; ++r) {
                float p = __expf(mag[nt][r] - m[r]);
                mag[nt][r] = p;
                ps[r] += p;
            }
        #pragma unroll
        for (int d = 1; d < 16; d <<= 1)
            #pragma unroll
            for (int r = 0; r < 4; ++r)
                ps[r] += __shfl_xor(ps[r], d, 16);
        #pragma unroll
        for (int r = 0; r < 4; ++r)
            l[r] = fmaf(l[r], al[r], ps[r]);

        #pragma unroll
        for (int h = 0; h < 4; ++h)
            #pragma unroll
            for (int r = 0; r < 4; ++r) { Or[h][r] *= al[r]; Oi[h][r] *= al[r]; }

        #pragma unroll
        for (int nt = 0; nt < 4; ++nt)
            #pragma unroll
            for (int r = 0; r < 4; ++r)
                Pw[(quad*4 + r) * PLDS + nt*16 + lm] = f2bf_s(mag[nt][r]);
        short8 Af0 = *(const short8*)&Pw[lm * PLDS + quad*8];
        short8 Af1 = *(const short8*)&Pw[lm * PLDS + 32 + quad*8];

        #pragma unroll
        for (int ht = 0; ht < 4; ++ht) {
            const short* vr0 = Vrb + (size_t)(ht*16 + lm) * TT + kb + quad*8;
            const short* vi0 = Vib + (size_t)(ht*16 + lm) * TT + kb + quad*8;
            short8 br0 = *(const short8*)(vr0);
            short8 br1 = *(const short8*)(vr0 + 32);
            short8 bi0 = *(const short8*)(vi0);
            short8 bi1 = *(const short8*)(vi0 + 32);
            Or[ht] = __builtin_amdgcn_mfma_f32_16x16x32_bf16(Af0, br0, Or[ht], 0,0,0);
            Or[ht] = __builtin_amdgcn_mfma_f32_16x16x32_bf16(Af1, br1, Or[ht], 0,0,0);
            Oi[ht] = __builtin_amdgcn_mfma_f32_16x16x32_bf16(Af0, bi0, Oi[ht], 0,0,0);
            Oi[ht] = __builtin_amdgcn_mfma_f32_16x16x32_bf16(Af1, bi1, Oi[ht], 0,0,0);
        }
    }

    __syncthreads();

    #pragma unroll
    for (int ht = 0; ht < 4; ++ht)
        #pragma unroll
        for (int r = 0; r < 4; ++r) {
            comb[wave][quad*4 + r][ht*16 + lm]      = Or[ht][r];
            comb[wave][quad*4 + r][64 + ht*16 + lm] = Oi[ht][r];
        }
    if (lm == 0) {
        #pragma unroll
        for (int r = 0; r < 4; ++r) {
            cmw[wave][quad*4 + r] = m[r];
            clw[wave][quad*4 + r] = l[r];
        }
    }
    __syncthreads();

    for (int e = tid; e < 16*128; e += 256) {
        int q = e >> 7, h = e & 127;
        float mstar = fmaxf(fmaxf(cmw[0][q], cmw[1][q]), fmaxf(cmw[2][q], cmw[3][q]));
        float osum = 0.f, lsum = 0.f;
        #pragma unroll
        for (int w = 0; w < 4; ++w) {
            float f = __expf(cmw[w][q] - mstar);
            osum = fmaf(f, comb[w][q][h], osum);
            lsum = fmaf(f, clw[w][q], lsum);
        }
        float res = osum / lsum;
        int comp = h >> 6, hh = h & 63;
        out[(size_t)comp * NST + ((size_t)(b*TT + qbase + q)) * HH + hh] = res;
    }
}

extern "C" void kernel_launch(void* const* d_in, const int* in_sizes, int n_in,
                              void* d_out, int out_size, void* d_ws, size_t ws_size,
                              hipStream_t stream)
{
    const float* xr  = (const float*)d_in[0];
    const float* xi  = (const float*)d_in[1];
    const float* Wkr = (const float*)d_in[2];
    const float* Wki = (const float*)d_in[3];
    const float* Wqr = (const float*)d_in[4];
    const float* Wqi = (const float*)d_in[5];
    const float* Wvr = (const float*)d_in[6];
    const float* Wvi = (const float*)d_in[7];

    short* Bt = (short*)d_ws;                               // 1.5 MB
    short* G  = (short*)((char*)d_ws + (2u  << 20));        // 12 MB  [16384][384]
    short* VT = (short*)((char*)d_ws + (16u << 20));        // 4 MB   [2][8][64][2048]
    float* out = (float*)d_out;

    prep_kernel<<<NN, 256, 0, stream>>>(Wkr, Wki, Wqr, Wqi, Wvr, Wvi, Bt);

    dim3 g1(NROW / 64, 3);
    proj_gemm<<<g1, 256, 0, stream>>>(xr, xi, Bt, G, VT);

    dim3 g3(TT / 16, BB);
    attn_kernel<<<g3, 256, 0, stream>>>(G, VT, out);
}

// Round 5
// 328.473 us; speedup vs baseline: 1.1418x; 1.1418x over previous
//
#include <hip/hip_runtime.h>
#include <hip/hip_bf16.h>
#include <math.h>

#define BB 8
#define TT 2048
#define CC 1024
#define HH 64
#define NROW (BB*TT)          // 16384
#define NST (NROW*HH)         // 1048576 elements per output component
#define KK2 2048              // combined GEMM K = 2C
#define NN 384                // Bt rows (6 components)
#define GN 256                // G cols: [kr|ki|qr|qi]  (512 B rows, exact lines)
#define VTP 2080              // VT row stride in elements (4160 B, breaks 4KB aliasing)

typedef __attribute__((ext_vector_type(8))) short short8;
typedef __attribute__((ext_vector_type(4))) float f32x4;

static __device__ inline unsigned pk_bf16(float a, float b) {
    __hip_bfloat162 h = __float22bfloat162_rn(make_float2(a, b));
    unsigned u; __builtin_memcpy(&u, &h, 4); return u;
}
static __device__ inline short f2bf_s(float a) {
    __hip_bfloat16 h = __float2bfloat16(a);
    short s; __builtin_memcpy(&s, &h, 2); return s;
}
static __device__ inline short8 neg8(short8 a) {
    short8 r;
    #pragma unroll
    for (int i = 0; i < 8; ++i) r[i] = a[i] ^ (short)0x8000;
    return r;
}

// ---------------------------------------------------------------------------
// Kernel 0: build Bt[n][k] bf16. n = 64*g + h, g in [kr,ki,qr,qi,vr,vi];
// real: [Wr;-Wi], imag: [Wi;Wr].
// ---------------------------------------------------------------------------
__global__ __launch_bounds__(256) void prep_kernel(
    const float* __restrict__ Wkr, const float* __restrict__ Wki,
    const float* __restrict__ Wqr, const float* __restrict__ Wqi,
    const float* __restrict__ Wvr, const float* __restrict__ Wvi,
    short* __restrict__ Bt)
{
    const int n = blockIdx.x;
    const int g = n >> 6, h = n & 63;
    const int p = g >> 1;
    const bool im = g & 1;
    const float* Wr = (p == 0) ? Wkr : (p == 1) ? Wqr : Wvr;
    const float* Wi = (p == 0) ? Wki : (p == 1) ? Wqi : Wvi;
    const float* W1 = im ? Wi : Wr;
    const float* W2 = im ? Wr : Wi;
    const float s2 = im ? 1.f : -1.f;

    #pragma unroll
    for (int j = 0; j < 8; ++j) {
        int k = threadIdx.x + 256 * j;
        float v = (k < CC) ? W1[k * HH + h] : s2 * W2[(k - CC) * HH + h];
        Bt[(size_t)n * KK2 + k] = f2bf_s(v);
    }
}

// ---------------------------------------------------------------------------
// Kernel 1: bf16 MFMA GEMM. BM=128 BN=64 BK=64, grid (128, 6) = 768 blocks
// (all co-resident; same-row blocks land on the same XCD for L2 A-sharing).
// y = component: 0..3 -> G[16384][256]; 4,5 -> VT[comp][b][h][t] (LDS-transposed,
// fully-coalesced 16B stores).
// ---------------------------------------------------------------------------
#define BK 64
#define LDP 72
#define STP 136   // sT row stride (elements), 16B-aligned

__global__ __launch_bounds__(256) void proj_gemm(
    const float* __restrict__ xr, const float* __restrict__ xi,
    const short* __restrict__ Bt,
    short* __restrict__ G, short* __restrict__ VT)
{
    __shared__ __attribute__((aligned(16))) short sA[128 * LDP];  // 18.4 KB
    __shared__ __attribute__((aligned(16))) short sB[64 * LDP];   // 9.2 KB

    const int tid = threadIdx.x;
    const int mbase = blockIdx.x * 128;
    const int comp = blockIdx.y;                 // 0..5

    const int wave = tid >> 6, lane = tid & 63;
    const int wr = wave >> 1, wc = wave & 1;     // 64-row half, 32-col half
    const int quad = lane >> 4, lm = lane & 15;

    f32x4 acc[4][2] = {};

    for (int ks = 0; ks < KK2 / BK; ++ks) {
        const float* __restrict__ srcA = (ks < 16) ? xr : xi;
        const int kc = (ks & 15) * BK;
        float4 av[8];
        #pragma unroll
        for (int j = 0; j < 8; ++j) {
            int id = tid + 256 * j;
            int r = id >> 4, c4 = id & 15;
            av[j] = *(const float4*)&srcA[(size_t)(mbase + r) * CC + kc + c4 * 4];
        }
        uint4 bv[2];
        #pragma unroll
        for (int j = 0; j < 2; ++j) {
            int id = tid + 256 * j;
            int nn = id >> 3, c8 = id & 7;
            bv[j] = *(const uint4*)&Bt[(size_t)(comp*64 + nn) * KK2 + ks * BK + c8 * 8];
        }
        __syncthreads();

        #pragma unroll
        for (int j = 0; j < 8; ++j) {
            int id = tid + 256 * j;
            int r = id >> 4, c4 = id & 15;
            uint2 pkd;
            pkd.x = pk_bf16(av[j].x, av[j].y);
            pkd.y = pk_bf16(av[j].z, av[j].w);
            *(uint2*)&sA[r * LDP + c4 * 4] = pkd;
        }
        #pragma unroll
        for (int j = 0; j < 2; ++j) {
            int id = tid + 256 * j;
            int nn = id >> 3, c8 = id & 7;
            *(uint4*)&sB[nn * LDP + c8 * 8] = bv[j];
        }
        __syncthreads();

        #pragma unroll
        for (int kk = 0; kk < 2; ++kk) {
            short8 af[4], bf[2];
            #pragma unroll
            for (int mi = 0; mi < 4; ++mi)
                af[mi] = *(const short8*)&sA[(64*wr + 16*mi + lm) * LDP + kk*32 + quad*8];
            #pragma unroll
            for (int ni = 0; ni < 2; ++ni)
                bf[ni] = *(const short8*)&sB[(32*wc + 16*ni + lm) * LDP + kk*32 + quad*8];
            #pragma unroll
            for (int mi = 0; mi < 4; ++mi)
                #pragma unroll
                for (int ni = 0; ni < 2; ++ni)
                    acc[mi][ni] = __builtin_amdgcn_mfma_f32_16x16x32_bf16(
                        af[mi], bf[ni], acc[mi][ni], 0, 0, 0);
        }
    }

    __syncthreads();   // LDS reads of last k-iter done; reuse sA for epilogue

    if (comp < 4) {
        // ---- stage 128x64 bf16 tile, then fully-coalesced 16B stores to G ----
        short* sG = sA;   // [128][LDP]
        #pragma unroll
        for (int mi = 0; mi < 4; ++mi)
            #pragma unroll
            for (int ni = 0; ni < 2; ++ni)
                #pragma unroll
                for (int r = 0; r < 4; ++r)
                    sG[(64*wr + 16*mi + quad*4 + r) * LDP + 32*wc + 16*ni + lm] =
                        f2bf_s(acc[mi][ni][r]);
        __syncthreads();
        #pragma unroll
        for (int j = 0; j < 4; ++j) {
            int id = tid + 256 * j;
            int row = id >> 3, c8 = id & 7;       // 8 x 16B per row
            uint4 v = *(const uint4*)&sG[row * LDP + c8 * 8];
            *(uint4*)&G[(size_t)(mbase + row) * GN + comp*64 + c8*8] = v;
        }
    } else {
        // ---- transpose 128t x 64h in LDS, coalesced 16B stores to VT ----
        short* sT = sA;   // [64][STP]
        const int vcomp = comp - 4;
        const int b = mbase >> 11;
        const int tb = mbase & 2047;
        #pragma unroll
        for (int mi = 0; mi < 4; ++mi)
            #pragma unroll
            for (int ni = 0; ni < 2; ++ni)
                #pragma unroll
                for (int r = 0; r < 4; ++r)
                    sT[(32*wc + 16*ni + lm) * STP + 64*wr + 16*mi + quad*4 + r] =
                        f2bf_s(acc[mi][ni][r]);
        __syncthreads();
        #pragma unroll
        for (int j = 0; j < 4; ++j) {
            int id = tid + 256 * j;
            int h = id >> 4, c = id & 15;         // 16 x 16B per h-row
            uint4 v = *(const uint4*)&sT[h * STP + c * 8];
            *(uint4*)&VT[(((size_t)vcomp*BB + b)*64 + h)*VTP + tb + c*8] = v;
        }
    }
}

// ---------------------------------------------------------------------------
// Kernel 2: MFMA flash attention. Wave-autonomous 16-row q-tiles; 4 waves/block
// split the k-range (kt % 4 == wave) and merge (m,l,O) via LDS at the end.
// grid = (128 q-tiles, 8 b), 256 threads, longest q-tiles first.
// ---------------------------------------------------------------------------
#define PLDS 72

__global__ __launch_bounds__(256) void attn_kernel(
    const short* __restrict__ G,
    const short* __restrict__ VT,
    float* __restrict__ out)
{
    __shared__ float comb[4][16][128];
    __shared__ float cmw[4][16], clw[4][16];

    const int tid = threadIdx.x;
    const int wave = tid >> 6, lane = tid & 63;
    const int quad = lane >> 4, lm = lane & 15;
    const int j = (int)(gridDim.x - 1) - (int)blockIdx.x;   // longest first
    const int b = blockIdx.y;
    const int qbase = j * 16;
    const int nkt = (j >> 2) + 1;    // k-tiles of 64 tokens

    const short* Qrow = G + ((size_t)(b*TT + qbase + lm)) * GN + 128;
    short8 A1[4], A2[4];
    #pragma unroll
    for (int ks = 0; ks < 4; ++ks)
        A1[ks] = *(const short8*)(Qrow + ks*32 + quad*8);
    A2[0] = A1[2]; A2[1] = A1[3];
    A2[2] = neg8(A1[0]); A2[3] = neg8(A1[1]);

    f32x4 Or[4], Oi[4];
    #pragma unroll
    for (int h = 0; h < 4; ++h)
        #pragma unroll
        for (int r = 0; r < 4; ++r) { Or[h][r] = 0.f; Oi[h][r] = 0.f; }
    float m[4], l[4];
    #pragma unroll
    for (int r = 0; r < 4; ++r) { m[r] = -INFINITY; l[r] = 0.f; }

    short* Pw = (short*)&comb[wave][0][0];
    const short* Vrb = VT + (size_t)b * 64 * VTP;
    const short* Vib = VT + ((size_t)BB + b) * 64 * VTP;

    for (int kt = wave; kt < nkt; kt += 4) {
        const int kb = kt * 64;
        const short* Kt = G + ((size_t)(b*TT + kb)) * GN;

        f32x4 mag[4];
        #pragma unroll
        for (int nt = 0; nt < 4; ++nt) {
            const short* Krow = Kt + (size_t)(nt*16 + lm) * GN;
            short8 Bf[4];
            #pragma unroll
            for (int ks = 0; ks < 4; ++ks)
                Bf[ks] = *(const short8*)(Krow + ks*32 + quad*8);
            f32x4 sr = {0.f,0.f,0.f,0.f}, si = {0.f,0.f,0.f,0.f};
            #pragma unroll
            for (int ks = 0; ks < 4; ++ks) {
                sr = __builtin_amdgcn_mfma_f32_16x16x32_bf16(A1[ks], Bf[ks], sr, 0,0,0);
                si = __builtin_amdgcn_mfma_f32_16x16x32_bf16(A2[ks], Bf[ks], si, 0,0,0);
            }
            int tok = kb + nt*16 + lm;
            #pragma unroll
            for (int r = 0; r < 4; ++r) {
                float v = sqrtf(fmaf(sr[r], sr[r], fmaf(si[r], si[r], 1e-4f))) * 0.125f;
                int qrow = qbase + quad*4 + r;
                mag[nt][r] = (tok > qrow) ? -INFINITY : v;
            }
        }

        float tm[4];
        #pragma unroll
        for (int r = 0; r < 4; ++r)
            tm[r] = fmaxf(fmaxf(mag[0][r], mag[1][r]), fmaxf(mag[2][r], mag[3][r]));
        #pragma unroll
        for (int d = 1; d < 16; d <<= 1)
            #pragma unroll
            for (int r = 0; r < 4; ++r)
                tm[r] = fmaxf(tm[r], __shfl_xor(tm[r], d, 16));

        float al[4], ps[4];
        #pragma unroll
        for (int r = 0; r < 4; ++r) {
            float mn = fmaxf(m[r], tm[r]);
            al[r] = __expf(m[r] - mn);
            m[r] = mn;
            ps[r] = 0.f;
        }
        #pragma unroll
        for (int nt = 0; nt < 4; ++nt)
            #pragma unroll
            for (int r = 0; r < 4; ++r) {
                float p = __expf(mag[nt][r] - m[r]);
                mag[nt][r] = p;
                ps[r] += p;
            }
        #pragma unroll
        for (int d = 1; d < 16; d <<= 1)
            #pragma unroll
            for (int r = 0; r < 4; ++r)
                ps[r] += __shfl_xor(ps[r], d, 16);
        #pragma unroll
        for (int r = 0; r < 4; ++r)
            l[r] = fmaf(l[r], al[r], ps[r]);

        #pragma unroll
        for (int h = 0; h < 4; ++h)
            #pragma unroll
            for (int r = 0; r < 4; ++r) { Or[h][r] *= al[r]; Oi[h][r] *= al[r]; }

        #pragma unroll
        for (int nt = 0; nt < 4; ++nt)
            #pragma unroll
            for (int r = 0; r < 4; ++r)
                Pw[(quad*4 + r) * PLDS + nt*16 + lm] = f2bf_s(mag[nt][r]);
        short8 Af0 = *(const short8*)&Pw[lm * PLDS + quad*8];
        short8 Af1 = *(const short8*)&Pw[lm * PLDS + 32 + quad*8];

        #pragma unroll
        for (int ht = 0; ht < 4; ++ht) {
            const short* vr0 = Vrb + (size_t)(ht*16 + lm) * VTP + kb + quad*8;
            const short* vi0 = Vib + (size_t)(ht*16 + lm) * VTP + kb + quad*8;
            short8 br0 = *(const short8*)(vr0);
            short8 br1 = *(const short8*)(vr0 + 32);
            short8 bi0 = *(const short8*)(vi0);
            short8 bi1 = *(const short8*)(vi0 + 32);
            Or[ht] = __builtin_amdgcn_mfma_f32_16x16x32_bf16(Af0, br0, Or[ht], 0,0,0);
            Or[ht] = __builtin_amdgcn_mfma_f32_16x16x32_bf16(Af1, br1, Or[ht], 0,0,0);
            Oi[ht] = __builtin_amdgcn_mfma_f32_16x16x32_bf16(Af0, bi0, Oi[ht], 0,0,0);
            Oi[ht] = __builtin_amdgcn_mfma_f32_16x16x32_bf16(Af1, bi1, Oi[ht], 0,0,0);
        }
    }

    __syncthreads();

    #pragma unroll
    for (int ht = 0; ht < 4; ++ht)
        #pragma unroll
        for (int r = 0; r < 4; ++r) {
            comb[wave][quad*4 + r][ht*16 + lm]      = Or[ht][r];
            comb[wave][quad*4 + r][64 + ht*16 + lm] = Oi[ht][r];
        }
    if (lm == 0) {
        #pragma unroll
        for (int r = 0; r < 4; ++r) {
            cmw[wave][quad*4 + r] = m[r];
            clw[wave][quad*4 + r] = l[r];
        }
    }
    __syncthreads();

    for (int e = tid; e < 16*128; e += 256) {
        int q = e >> 7, h = e & 127;
        float mstar = fmaxf(fmaxf(cmw[0][q], cmw[1][q]), fmaxf(cmw[2][q], cmw[3][q]));
        float osum = 0.f, lsum = 0.f;
        #pragma unroll
        for (int w = 0; w < 4; ++w) {
            float f = __expf(cmw[w][q] - mstar);
            osum = fmaf(f, comb[w][q][h], osum);
            lsum = fmaf(f, clw[w][q], lsum);
        }
        float res = osum / lsum;
        int comp = h >> 6, hh = h & 63;
        out[(size_t)comp * NST + ((size_t)(b*TT + qbase + q)) * HH + hh] = res;
    }
}

extern "C" void kernel_launch(void* const* d_in, const int* in_sizes, int n_in,
                              void* d_out, int out_size, void* d_ws, size_t ws_size,
                              hipStream_t stream)
{
    const float* xr  = (const float*)d_in[0];
    const float* xi  = (const float*)d_in[1];
    const float* Wkr = (const float*)d_in[2];
    const float* Wki = (const float*)d_in[3];
    const float* Wqr = (const float*)d_in[4];
    const float* Wqi = (const float*)d_in[5];
    const float* Wvr = (const float*)d_in[6];
    const float* Wvi = (const float*)d_in[7];

    short* Bt = (short*)d_ws;                               // 1.5 MB
    short* G  = (short*)((char*)d_ws + (2u  << 20));        // 8 MB  [16384][256]
    short* VT = (short*)((char*)d_ws + (11u << 20));        // 4.3 MB [2][8][64][VTP]
    float* out = (float*)d_out;

    prep_kernel<<<NN, 256, 0, stream>>>(Wkr, Wki, Wqr, Wqi, Wvr, Wvi, Bt);

    dim3 g1(NROW / 128, 6);
    proj_gemm<<<g1, 256, 0, stream>>>(xr, xi, Bt, G, VT);

    dim3 g3(TT / 16, BB);
    attn_kernel<<<g3, 256, 0, stream>>>(G, VT, out);
}